// Round 1
// baseline (1486.963 us; speedup 1.0000x reference)
//
#include <hip/hip_runtime.h>
#include <hip/hip_bf16.h>

#define BB   128
#define SS   256
#define DD   512
#define HH   1024
#define NCC  128
#define NCLS 129
#define G4   4096   // 4*HH, gate-interleaved: j = hcol*4 + gate (f,i,g,o)
#define NWG  256    // persistent grid size

typedef __attribute__((ext_vector_type(8)))  short  short8;
typedef __attribute__((ext_vector_type(16))) float  f32x16;

static __device__ __forceinline__ float sigm(float x)  { return 1.0f / (1.0f + __expf(-x)); }
static __device__ __forceinline__ float tanh_(float x) { return 1.0f - 2.0f / (__expf(2.0f * x) + 1.0f); }
static __device__ __forceinline__ unsigned short f2b(float v) {
    __hip_bfloat16 h = __float2bfloat16(v);
    return *reinterpret_cast<unsigned short*>(&h);
}
static __device__ __forceinline__ short8 ld16(const unsigned short* p) {
    return *reinterpret_cast<const short8*>(p);
}

// ---------------- zero-init h buffer 0 and flag block ----------------
__global__ void k_init(unsigned short* __restrict__ hb0, int* __restrict__ flags) {
    int i = blockIdx.x * 256 + threadIdx.x;
    if (i < BB * HH) hb0[i] = 0;
    if (i < 16384) flags[i] = 0;   // 256 leaf slots + 4 go slots, 128B-strided
}

// ---------------- Wh -> bf16, transposed, gate-interleaved ----------------
__global__ void k_conv_wh(const float* __restrict__ Wfh, const float* __restrict__ Wih,
                          const float* __restrict__ Wgh, const float* __restrict__ Woh,
                          unsigned short* __restrict__ WhT) {
    __shared__ float t[32][33];
    int g = blockIdx.z;
    const float* W = (g == 0) ? Wfh : (g == 1) ? Wih : (g == 2) ? Wgh : Woh;
    int h0 = blockIdx.x * 32, k0 = blockIdx.y * 32;
    int tx = threadIdx.x & 31, ty = threadIdx.x >> 5;
    for (int r = 0; r < 4; r++) {
        int k = ty + r * 8;
        t[k][tx] = W[(size_t)(k0 + k) * HH + h0 + tx];
    }
    __syncthreads();
    for (int r = 0; r < 4; r++) {
        int hl = ty + r * 8;
        int j  = (h0 + hl) * 4 + g;
        WhT[(size_t)j * HH + k0 + tx] = f2b(t[tx][hl]);
    }
}

// ---------------- proj[c][j] = emb[c,:] @ Wx[:,hcol] + b ----------------
__global__ void k_proj(const float* __restrict__ emb,
                       const float* __restrict__ Wfx, const float* __restrict__ Wix,
                       const float* __restrict__ Wgx, const float* __restrict__ Wox,
                       const float* __restrict__ bf_, const float* __restrict__ bi_,
                       const float* __restrict__ bg_, const float* __restrict__ bo_,
                       float* __restrict__ proj) {
    int c = blockIdx.y;
    int j = blockIdx.x * 256 + threadIdx.x;
    int hcol = j >> 2, g = j & 3;
    const float* Wx = (g == 0) ? Wfx : (g == 1) ? Wix : (g == 2) ? Wgx : Wox;
    const float* bb = (g == 0) ? bf_ : (g == 1) ? bi_ : (g == 2) ? bg_ : bo_;
    float acc = bb[hcol];
    const float* er = emb + (size_t)c * DD;
    for (int d = 0; d < DD; d++) acc += er[d] * Wx[(size_t)d * HH + hcol];
    proj[(size_t)c * G4 + j] = acc;
}

// ---- L2-bypassing 16B load from rolling base (h is cross-XCD dynamic data)
#define LDAB(d, B, L) asm volatile("global_load_dwordx4 %0, %1, off offset:" L " sc0 sc1" \
                                   : "=v"(d) : "v"(B))
// 4 contiguous 1KB loads then advance base 4KB (13-bit offset limit)
#define LD4(A, I) do { \
    LDAB(A[(I)+0], p, "0"); LDAB(A[(I)+1], p, "1024"); \
    LDAB(A[(I)+2], p, "2048"); LDAB(A[(I)+3], p, "3072"); p += 4096; } while (0)
#define LD8(A) do { LD4(A,0); LD4(A,4); } while (0)

// ---- waitcnt with data-tie so MFMAs can't be scheduled before the wait
#define WAITB(N, A) asm volatile("s_waitcnt vmcnt(" N ")" : \
    "+v"(A[0]),"+v"(A[1]),"+v"(A[2]),"+v"(A[3]),"+v"(A[4]),"+v"(A[5]),"+v"(A[6]),"+v"(A[7]))

#define MM(a, b, c) __builtin_amdgcn_mfma_f32_32x32x16_bf16(a, b, c, 0, 0, 0)

// 8 A-fragments x 2 col-tiles; 4 acc chains (tile x frag-parity) so the
// same-acc reuse gap is 3 MFMAs (~24 cyc) -- covers MFMA latency.
#define MF8x2(A, KB) do { \
    t0e = MM(A[0], breg[((KB)+0)*2+0], t0e); t1e = MM(A[0], breg[((KB)+0)*2+1], t1e); \
    t0o = MM(A[1], breg[((KB)+1)*2+0], t0o); t1o = MM(A[1], breg[((KB)+1)*2+1], t1o); \
    t0e = MM(A[2], breg[((KB)+2)*2+0], t0e); t1e = MM(A[2], breg[((KB)+2)*2+1], t1e); \
    t0o = MM(A[3], breg[((KB)+3)*2+0], t0o); t1o = MM(A[3], breg[((KB)+3)*2+1], t1o); \
    t0e = MM(A[4], breg[((KB)+4)*2+0], t0e); t1e = MM(A[4], breg[((KB)+4)*2+1], t1e); \
    t0o = MM(A[5], breg[((KB)+5)*2+0], t0o); t1o = MM(A[5], breg[((KB)+5)*2+1], t1o); \
    t0e = MM(A[6], breg[((KB)+6)*2+0], t0e); t1e = MM(A[6], breg[((KB)+6)*2+1], t1e); \
    t0o = MM(A[7], breg[((KB)+7)*2+0], t0o); t1o = MM(A[7], breg[((KB)+7)*2+1], t1o); \
} while (0)

// 16 gathered proj loads (normal caching), completed by the poll's vmcnt(0)
#define PRLOAD(DSTA, CLSBUF) do { \
    _Pragma("unroll") \
    for (int r = 0; r < 16; r++) { \
        int row = (r & 3) + 8 * (r >> 2) + 4 * half; \
        const float* pa = proj + (size_t)CLSBUF[row] * G4 + jg; \
        asm volatile("global_load_dword %0, %1, off" : "=v"(DSTA[r]) \
                     : "v"((unsigned long long)pa)); \
    } \
} while (0)

// ---------------- persistent LSTM scan ----------------
// 256 WGs x 128 thr (2 waves). WG(mg = wg&3, ng = wg>>2): rows mg*32..+32,
// gate-cols ng*64..+64.
// K-SPLIT ACROSS WAVES: wave wv holds WhT fragments for BOTH 32-col tiles but
// only K-half wv (64 cols x 512 k = 256 regs, same breg budget as before) and
// global-loads only ITS 32KB half of the A-tile -> per-WG A traffic from LLC
// halves (64KB/step instead of 128KB/step; chip-wide 16MB/step vs 32MB/step).
// Each wave produces PARTIAL sums for both tiles (64 MFMAs, unchanged); the
// non-owned tile's partials are exchanged via an 8KB LDS buffer, then wave wv
// finishes tile wv (pr add + sigmoid + sg stash) exactly as before.
// h stored FRAGMENT-MAJOR: hF[mg][kk][lane][8bf16] so A-loads are contiguous
// sector-perfect 1KB streams (lane l: m = l&31, k = kk*16+(l>>5)*8+j).
// Sync per mg-group: leaves post flags[wg]; aggregator wave (WG mg<4, wave 0)
// polls its 64 leaves, posts go[mg]; everyone else polls go[mg] with a single
// lane-uniform load.
__global__ __launch_bounds__(128, 1)
void k_scan(const int* __restrict__ x, const float* __restrict__ proj,
            const unsigned short* __restrict__ WhT,
            unsigned short* __restrict__ hb0, unsigned short* __restrict__ hb1,
            float* __restrict__ hf32, int* __restrict__ flags) {
    const int wg = blockIdx.x, tid = threadIdx.x;
    const int lane = tid & 63, wv = tid >> 6;
    const int l31 = lane & 31, half = lane >> 5;
    const int mg = wg & 3, ng = wg >> 2;
    const int m0 = mg * 32, n0 = ng * 64;
    const int jg = n0 + wv * 32 + l31;       // this lane's OWNED gate-col

    // B fragments, K-half wv, both col-tiles interleaved:
    // breg[2*kk+t] = WhT[n0 + t*32 + l31][wv*512 + kk*16 + half*8 .. +8]
    short8 breg[64];
    {
        const unsigned short* B0 = WhT + (size_t)(n0 + l31)      * HH + wv * 512 + half * 8;
        const unsigned short* B1 = WhT + (size_t)(n0 + 32 + l31) * HH + wv * 512 + half * 8;
        #pragma unroll
        for (int kk = 0; kk < 32; kk++) {
            breg[2 * kk + 0] = ld16(B0 + kk * 16);
            breg[2 * kk + 1] = ld16(B1 + kk * 16);
        }
    }

    __shared__ float sg[32][68];      // sigmoided gates [row][gate-col]
    __shared__ float pbuf[2][16][64]; // cross-wave partial exchange
    __shared__ int   clsS[2][32];     // double-buffered class ids

    float Cst[4] = {0.0f, 0.0f, 0.0f, 0.0f};
    const int urow = tid & 31, uq = tid >> 5;

    if (tid < 32) clsS[0][tid] = x[(size_t)(m0 + tid) * SS];
    __syncthreads();

    // fragment-major bases: hF byte offset = mg*65536 + kk*1024 + lane*16;
    // wave wv reads fragments kk = wv*32 .. +32 (its K-half)
    const unsigned long long ab0 =
        (unsigned long long)((char*)hb0 + mg * 65536 + wv * 32768 + lane * 16);
    const unsigned long long ab1 =
        (unsigned long long)((char*)hb1 + mg * 65536 + wv * 32768 + lane * 16);
    // producer store base: cell = urow + 32*(uq>>1), sub = (uq&1)*8 bytes
    const unsigned long long sb0 = (unsigned long long)((char*)hb0 + mg * 65536
        + ng * 1024 + (urow + ((uq >> 1) << 5)) * 16 + (uq & 1) * 8);
    const unsigned long long sb1 = (unsigned long long)((char*)hb1 + mg * 65536
        + ng * 1024 + (urow + ((uq >> 1) << 5)) * 16 + (uq & 1) * 8);

    const unsigned long long postAddr = (unsigned long long)(flags + (size_t)wg * 32);
    const unsigned long long leafAddr =
        (unsigned long long)(flags + ((size_t)(lane << 2) + mg) * 32);
    const unsigned long long goAddr =
        (unsigned long long)(flags + (size_t)(8192 + mg * 32));
    const bool isAggWave = (ng == 0) && (wv == 0);

    float pr[16];
    PRLOAD(pr, clsS[0]);            // step-0 proj gather (drained by first WAITB)

    for (int s = 0; s < SS; s++) {
        const int cur = s & 1;
        unsigned long long p = cur ? ab1 : ab0;
        const unsigned long long sb = cur ? sb0 : sb1;   // store to the OTHER buffer

        // ---- pipelined A loads: 4 batches x 8 x 1KB contiguous (32KB = K-half) ----
        short8 b0[8], b1[8], b2[8], b3[8];
        LD8(b0);
        LD8(b1);
        LD8(b2);

        f32x16 t0e, t0o, t1e, t1o;
        #pragma unroll
        for (int r = 0; r < 16; r++) { t0e[r] = 0.0f; t0o[r] = 0.0f; t1e[r] = 0.0f; t1o[r] = 0.0f; }

        WAITB("16", b0);      // (first iter: also drains the 16 pr loads, oldest)
        MF8x2(b0, 0);
        LD8(b3);
        WAITB("16", b1);
        MF8x2(b1, 8);
        WAITB("8", b2);
        MF8x2(b2, 16);
        WAITB("0", b3);
        MF8x2(b3, 24);

        // ---- exchange non-owned tile partials through LDS ----
        #pragma unroll
        for (int r = 0; r < 16; r++)
            pbuf[wv][r][lane] = (wv == 0) ? (t1e[r] + t1o[r]) : (t0e[r] + t0o[r]);
        __syncthreads();

        // ---- epilogue: own partial + partner partial + preloaded proj, sigmoid ----
        // C/D layout (m74/m101): col = lane&31, row = (r&3) + 8*(r>>2) + 4*(lane>>5)
        #pragma unroll
        for (int r = 0; r < 16; r++) {
            float own = (wv == 0) ? (t0e[r] + t0o[r]) : (t1e[r] + t1o[r]);
            int row = (r & 3) + 8 * (r >> 2) + 4 * half;
            sg[row][wv * 32 + l31] = sigm(own + pbuf[wv ^ 1][r][lane] + pr[r]);
        }
        __syncthreads();

        // ---- pointwise: thread owns (row = tid&31, hcols uq*4..+4) ----
        {
            const float rr = (clsS[cur][urow] > 0) ? 1.0f : 0.0f;
            unsigned short hv[4];
            #pragma unroll
            for (int q = 0; q < 4; q++) {
                float4 gq = *reinterpret_cast<const float4*>(&sg[urow][uq * 16 + q * 4]);
                float cn = (gq.z * gq.y + Cst[q] * gq.x) * rr;   // (g*i + C*f)*r
                Cst[q] = cn;
                float hvv = gq.w * tanh_(cn);
                hv[q] = f2b(hvv);
                if (s == SS - 1)
                    hf32[(size_t)(m0 + urow) * HH + ng * 16 + uq * 4 + q] = hvv;
            }
            unsigned long long pk = (unsigned long long)hv[0]
                                  | ((unsigned long long)hv[1] << 16)
                                  | ((unsigned long long)hv[2] << 32)
                                  | ((unsigned long long)hv[3] << 48);
            asm volatile("global_store_dwordx2 %0, %1, off sc0 sc1" :: "v"(sb), "v"(pk) : "memory");
            if (s + 1 < SS && tid < 32)
                clsS[cur ^ 1][tid] = x[(size_t)(m0 + tid) * SS + s + 1];
        }

        // ---- barrier: leaves -> aggregator wave -> go word ----
        if (s < SS - 1) {
            asm volatile("s_waitcnt vmcnt(0)" ::: "memory");   // h-store drained at L3
            __syncthreads();
            if (tid == 0) {
                int fv = s + 1;
                asm volatile("global_store_dword %0, %1, off sc0 sc1"
                             :: "v"(postAddr), "v"(fv) : "memory");
            }
            PRLOAD(pr, clsS[cur ^ 1]);     // next step's proj gather, rides the poll
            if (isAggWave) {
                int got;
                do {
                    asm volatile("global_load_dword %0, %1, off sc0 sc1\n\t"
                                 "s_waitcnt vmcnt(0)"
                                 : "=v"(got) : "v"(leafAddr) : "memory");
                } while (__ballot(got >= s + 1) != ~0ull);
                if (tid == 0) {
                    int fv = s + 1;
                    asm volatile("global_store_dword %0, %1, off sc0 sc1"
                                 :: "v"(goAddr), "v"(fv) : "memory");
                }
            } else {
                int got;
                do {   // lane-uniform single-line poll
                    asm volatile("global_load_dword %0, %1, off sc0 sc1\n\t"
                                 "s_waitcnt vmcnt(0)"
                                 : "=v"(got) : "v"(goAddr) : "memory");
                } while (got < s + 1);
            }
        }
    }
}

// ---------------- final projection + log_softmax ----------------
__global__ void k_final(const float* __restrict__ hf32, const float* __restrict__ Wph,
                        const float* __restrict__ bp, float* __restrict__ out) {
    __shared__ float red[128];
    int b = blockIdx.x, c = threadIdx.x;
    const float* hr = hf32 + (size_t)b * HH;
    float acc = bp[c];
    for (int k = 0; k < HH; k++) acc += hr[k] * Wph[(size_t)k * NCC + c];
    red[c] = acc;
    __syncthreads();
    for (int st = 64; st > 0; st >>= 1) {
        if (c < st) red[c] = fmaxf(red[c], red[c + st]);
        __syncthreads();
    }
    float m = red[0];
    __syncthreads();
    red[c] = __expf(acc - m);
    __syncthreads();
    for (int st = 64; st > 0; st >>= 1) {
        if (c < st) red[c] += red[c + st];
        __syncthreads();
    }
    out[(size_t)b * NCC + c] = acc - m - __logf(red[0]);
}

extern "C" void kernel_launch(void* const* d_in, const int* in_sizes, int n_in,
                              void* d_out, int out_size, void* d_ws, size_t ws_size,
                              hipStream_t stream) {
    const int*   x   = (const int*)  d_in[0];
    const float* emb = (const float*)d_in[1];
    const float* Wfx = (const float*)d_in[2];
    const float* Wfh = (const float*)d_in[3];
    const float* bf_ = (const float*)d_in[4];
    const float* Wix = (const float*)d_in[5];
    const float* Wih = (const float*)d_in[6];
    const float* bi_ = (const float*)d_in[7];
    const float* Wgx = (const float*)d_in[8];
    const float* Wgh = (const float*)d_in[9];
    const float* bg_ = (const float*)d_in[10];
    const float* Wox = (const float*)d_in[11];
    const float* Woh = (const float*)d_in[12];
    const float* bo_ = (const float*)d_in[13];
    const float* Wph = (const float*)d_in[14];
    const float* bp_ = (const float*)d_in[15];
    float* out = (float*)d_out;

    char* ws = (char*)d_ws;
    unsigned short* WhT   = (unsigned short*)(ws);              // 8 MB
    float*          proj  = (float*)(ws + 8388608);             // 2.02 MB -> ends 10502144
    int*            flags = (int*)(ws + 10502656);              // 64 KB (16384 ints)
    unsigned short* hb0   = (unsigned short*)(ws + 10568192);   // 256 KB
    unsigned short* hb1   = (unsigned short*)(ws + 10830336);   // 256 KB
    float*          hf32  = (float*)(ws + 11092480);            // 512 KB -> ends ~11.6 MB

    k_init<<<dim3(512), dim3(256), 0, stream>>>(hb0, flags);
    k_conv_wh<<<dim3(32, 32, 4), dim3(256), 0, stream>>>(Wfh, Wih, Wgh, Woh, WhT);
    k_proj<<<dim3(16, NCLS), dim3(256), 0, stream>>>(emb, Wfx, Wix, Wgx, Wox,
                                                     bf_, bi_, bg_, bo_, proj);
    k_scan<<<dim3(NWG), dim3(128), 0, stream>>>(x, proj, WhT, hb0, hb1, hf32, flags);
    k_final<<<dim3(128), dim3(128), 0, stream>>>(hf32, Wph, bp_, out);
}

// Round 2
// 1415.633 us; speedup vs baseline: 1.0504x; 1.0504x over previous
//
#include <hip/hip_runtime.h>
#include <hip/hip_bf16.h>

#define BB   128
#define SS   256
#define DD   512
#define HH   1024
#define NCC  128
#define NCLS 129
#define G4   4096   // 4*HH, gate-interleaved: j = hcol*4 + gate (f,i,g,o)
#define NWG  256    // persistent grid size

typedef __attribute__((ext_vector_type(8)))  short  short8;
typedef __attribute__((ext_vector_type(16))) float  f32x16;

static __device__ __forceinline__ float sigm(float x)  { return 1.0f / (1.0f + __expf(-x)); }
static __device__ __forceinline__ float tanh_(float x) { return 1.0f - 2.0f / (__expf(2.0f * x) + 1.0f); }
static __device__ __forceinline__ unsigned short f2b(float v) {
    __hip_bfloat16 h = __float2bfloat16(v);
    return *reinterpret_cast<unsigned short*>(&h);
}
static __device__ __forceinline__ short8 ld16(const unsigned short* p) {
    return *reinterpret_cast<const short8*>(p);
}

// ---------------- fused preamble: init + Wh-conv + proj (independent jobs) ----
// blocks [0,512)      : zero-init h buffer 0 and flag/counter block
// blocks [512,4608)   : Wh -> bf16, transposed, gate-interleaved
// blocks [4608,6672)  : proj[c][j] = emb[c,:] @ Wx[:,hcol] + b
__global__ void k_pre(unsigned short* __restrict__ hb0, int* __restrict__ flags,
                      const float* __restrict__ Wfh, const float* __restrict__ Wih,
                      const float* __restrict__ Wgh, const float* __restrict__ Woh,
                      unsigned short* __restrict__ WhT,
                      const float* __restrict__ emb,
                      const float* __restrict__ Wfx, const float* __restrict__ Wix,
                      const float* __restrict__ Wgx, const float* __restrict__ Wox,
                      const float* __restrict__ bf_, const float* __restrict__ bi_,
                      const float* __restrict__ bg_, const float* __restrict__ bo_,
                      float* __restrict__ proj) {
    __shared__ float t[32][33];
    const int bid = blockIdx.x;
    if (bid < 512) {
        int i = bid * 256 + threadIdx.x;
        if (i < BB * HH) hb0[i] = 0;
        if (i < 16384) flags[i] = 0;
        return;
    }
    if (bid < 4608) {
        int b = bid - 512;
        int bx = b & 31, by = (b >> 5) & 31, g = b >> 10;
        const float* W = (g == 0) ? Wfh : (g == 1) ? Wih : (g == 2) ? Wgh : Woh;
        int h0 = bx * 32, k0 = by * 32;
        int tx = threadIdx.x & 31, ty = threadIdx.x >> 5;
        for (int r = 0; r < 4; r++) {
            int k = ty + r * 8;
            t[k][tx] = W[(size_t)(k0 + k) * HH + h0 + tx];
        }
        __syncthreads();
        for (int r = 0; r < 4; r++) {
            int hl = ty + r * 8;
            int j  = (h0 + hl) * 4 + g;
            WhT[(size_t)j * HH + k0 + tx] = f2b(t[tx][hl]);
        }
        return;
    }
    {
        int b = bid - 4608;
        int c = b >> 4;
        int j = (b & 15) * 256 + threadIdx.x;
        int hcol = j >> 2, g = j & 3;
        const float* Wx = (g == 0) ? Wfx : (g == 1) ? Wix : (g == 2) ? Wgx : Wox;
        const float* bb = (g == 0) ? bf_ : (g == 1) ? bi_ : (g == 2) ? bg_ : bo_;
        float acc = bb[hcol];
        const float* er = emb + (size_t)c * DD;
        for (int d = 0; d < DD; d++) acc += er[d] * Wx[(size_t)d * HH + hcol];
        proj[(size_t)c * G4 + j] = acc;
    }
}

// ---- L2-bypassing 16B load from rolling base (h is cross-XCD dynamic data)
#define LDAB(d, B, L) asm volatile("global_load_dwordx4 %0, %1, off offset:" L " sc0 sc1" \
                                   : "=v"(d) : "v"(B))
// 4 contiguous 1KB loads then advance base 4KB (13-bit offset limit)
#define LD4(A, I) do { \
    LDAB(A[(I)+0], p, "0"); LDAB(A[(I)+1], p, "1024"); \
    LDAB(A[(I)+2], p, "2048"); LDAB(A[(I)+3], p, "3072"); p += 4096; } while (0)
#define LD16(A) do { LD4(A,0); LD4(A,4); LD4(A,8); LD4(A,12); } while (0)

// ---- waitcnt with data-tie so MFMAs can't be scheduled before the wait
#define WAITA(N, A) asm volatile("s_waitcnt vmcnt(" N ")" : \
    "+v"(A[0]),"+v"(A[1]),"+v"(A[2]),"+v"(A[3]),"+v"(A[4]),"+v"(A[5]),"+v"(A[6]),"+v"(A[7]), \
    "+v"(A[8]),"+v"(A[9]),"+v"(A[10]),"+v"(A[11]),"+v"(A[12]),"+v"(A[13]),"+v"(A[14]),"+v"(A[15]))

#define MF16(A, KB) do { \
    acc0 = __builtin_amdgcn_mfma_f32_32x32x16_bf16(A[0],  breg[(KB)+0],  acc0, 0,0,0); \
    acc1 = __builtin_amdgcn_mfma_f32_32x32x16_bf16(A[1],  breg[(KB)+1],  acc1, 0,0,0); \
    acc0 = __builtin_amdgcn_mfma_f32_32x32x16_bf16(A[2],  breg[(KB)+2],  acc0, 0,0,0); \
    acc1 = __builtin_amdgcn_mfma_f32_32x32x16_bf16(A[3],  breg[(KB)+3],  acc1, 0,0,0); \
    acc0 = __builtin_amdgcn_mfma_f32_32x32x16_bf16(A[4],  breg[(KB)+4],  acc0, 0,0,0); \
    acc1 = __builtin_amdgcn_mfma_f32_32x32x16_bf16(A[5],  breg[(KB)+5],  acc1, 0,0,0); \
    acc0 = __builtin_amdgcn_mfma_f32_32x32x16_bf16(A[6],  breg[(KB)+6],  acc0, 0,0,0); \
    acc1 = __builtin_amdgcn_mfma_f32_32x32x16_bf16(A[7],  breg[(KB)+7],  acc1, 0,0,0); \
    acc0 = __builtin_amdgcn_mfma_f32_32x32x16_bf16(A[8],  breg[(KB)+8],  acc0, 0,0,0); \
    acc1 = __builtin_amdgcn_mfma_f32_32x32x16_bf16(A[9],  breg[(KB)+9],  acc1, 0,0,0); \
    acc0 = __builtin_amdgcn_mfma_f32_32x32x16_bf16(A[10], breg[(KB)+10], acc0, 0,0,0); \
    acc1 = __builtin_amdgcn_mfma_f32_32x32x16_bf16(A[11], breg[(KB)+11], acc1, 0,0,0); \
    acc0 = __builtin_amdgcn_mfma_f32_32x32x16_bf16(A[12], breg[(KB)+12], acc0, 0,0,0); \
    acc1 = __builtin_amdgcn_mfma_f32_32x32x16_bf16(A[13], breg[(KB)+13], acc1, 0,0,0); \
    acc0 = __builtin_amdgcn_mfma_f32_32x32x16_bf16(A[14], breg[(KB)+14], acc0, 0,0,0); \
    acc1 = __builtin_amdgcn_mfma_f32_32x32x16_bf16(A[15], breg[(KB)+15], acc1, 0,0,0); \
} while (0)

// 16 gathered proj loads (normal caching), completed by the poll's vmcnt(0)
#define PRLOAD(DSTA, CLSBUF) do { \
    _Pragma("unroll") \
    for (int r = 0; r < 16; r++) { \
        int row = (r & 3) + 8 * (r >> 2) + 4 * half; \
        const float* pa = proj + (size_t)CLSBUF[row] * G4 + jg; \
        asm volatile("global_load_dword %0, %1, off" : "=v"(DSTA[r]) \
                     : "v"((unsigned long long)pa)); \
    } \
} while (0)

// ---------------- persistent LSTM scan ----------------
// 256 WGs x 128 thr (2 waves). WG(mg = wg&3, ng = wg>>2): rows mg*32..+32,
// gate-cols ng*64..+64. WhT slice in registers (full K).
// h stored FRAGMENT-MAJOR: hF[mg][kk][lane][8bf16] so A-loads are 64 x 1KB
// fully-contiguous sector-perfect streams (lane l: m = l&31, k = kk*16+(l>>5)*8+j).
// ONE-HOP barrier per mg-group: each WG fire-and-forget atomic_add(+1) on its
// group counter after its h-stores drain; all waves poll that single line until
// counter >= 64*(s+1). Removes the old leaf->aggregator->go double hop
// (~2 extra L3 round trips per step off the critical path). The 64 adds/line
// arrive time-spread, so same-line serialization hides under store-drain jitter.
__global__ __launch_bounds__(128, 1)
void k_scan(const int* __restrict__ x, const float* __restrict__ proj,
            const unsigned short* __restrict__ WhT,
            unsigned short* __restrict__ hb0, unsigned short* __restrict__ hb1,
            float* __restrict__ hf32, int* __restrict__ flags) {
    const int wg = blockIdx.x, tid = threadIdx.x;
    const int lane = tid & 63, wv = tid >> 6;
    const int l31 = lane & 31, half = lane >> 5;
    const int mg = wg & 3, ng = wg >> 2;
    const int m0 = mg * 32, n0 = ng * 64;
    const int jg = n0 + wv * 32 + l31;       // this lane's gate-col

    // B fragments: WhT[jg][k], k = kk*16 + half*8 + j  (256 regs)
    short8 breg[64];
    {
        const unsigned short* Bp = WhT + (size_t)jg * HH + half * 8;
        #pragma unroll
        for (int kk = 0; kk < 64; kk++) breg[kk] = ld16(Bp + kk * 16);
    }

    __shared__ float sg[32][68];    // sigmoided gates [row][gate-col]
    __shared__ int   clsS[2][32];   // double-buffered class ids

    float Cst[4] = {0.0f, 0.0f, 0.0f, 0.0f};
    const int urow = tid & 31, uq = tid >> 5;

    if (tid < 32) clsS[0][tid] = x[(size_t)(m0 + tid) * SS];
    __syncthreads();

    // fragment-major bases: hF byte offset = mg*65536 + kk*1024 + lane*16
    const unsigned long long ab0 =
        (unsigned long long)((char*)hb0 + mg * 65536 + lane * 16);
    const unsigned long long ab1 =
        (unsigned long long)((char*)hb1 + mg * 65536 + lane * 16);
    // producer store base: cell = urow + 32*(uq>>1), sub = (uq&1)*8 bytes
    const unsigned long long sb0 = (unsigned long long)((char*)hb0 + mg * 65536
        + ng * 1024 + (urow + ((uq >> 1) << 5)) * 16 + (uq & 1) * 8);
    const unsigned long long sb1 = (unsigned long long)((char*)hb1 + mg * 65536
        + ng * 1024 + (urow + ((uq >> 1) << 5)) * 16 + (uq & 1) * 8);

    // one counter line per mg-group (128B-strided, zeroed by k_pre)
    const unsigned long long ctrAddr =
        (unsigned long long)(flags + (size_t)(8192 + mg * 32));

    float pr[16];
    PRLOAD(pr, clsS[0]);            // step-0 proj gather (drained by first WAITA)

    for (int s = 0; s < SS; s++) {
        const int cur = s & 1;
        unsigned long long p = cur ? ab1 : ab0;
        const unsigned long long sb = cur ? sb0 : sb1;   // store to the OTHER buffer

        // ---- pipelined A loads: 4 groups x 16 x 1KB contiguous ----
        short8 a0[16], a1[16], a2[16], a3[16];
        LD16(a0);
        LD16(a1);

        f32x16 acc0, acc1;
        #pragma unroll
        for (int r = 0; r < 16; r++) { acc0[r] = 0.0f; acc1[r] = 0.0f; }

        WAITA("16", a0);
        LD16(a2);
        MF16(a0, 0);
        WAITA("16", a1);
        LD16(a3);
        MF16(a1, 16);
        WAITA("16", a2);
        MF16(a2, 32);
        WAITA("0", a3);
        MF16(a3, 48);

        // ---- epilogue: add preloaded proj, sigmoid, stash in LDS ----
        // C/D layout (m74/m101): col = lane&31, row = (r&3) + 8*(r>>2) + 4*(lane>>5)
        #pragma unroll
        for (int r = 0; r < 16; r++) {
            int row = (r & 3) + 8 * (r >> 2) + 4 * half;
            sg[row][wv * 32 + l31] = sigm(acc0[r] + acc1[r] + pr[r]);
        }
        __syncthreads();

        // ---- pointwise: thread owns (row = tid&31, hcols uq*4..+4) ----
        {
            const float rr = (clsS[cur][urow] > 0) ? 1.0f : 0.0f;
            unsigned short hv[4];
            #pragma unroll
            for (int q = 0; q < 4; q++) {
                float4 gq = *reinterpret_cast<const float4*>(&sg[urow][uq * 16 + q * 4]);
                float cn = (gq.z * gq.y + Cst[q] * gq.x) * rr;   // (g*i + C*f)*r
                Cst[q] = cn;
                float hvv = gq.w * tanh_(cn);
                hv[q] = f2b(hvv);
                if (s == SS - 1)
                    hf32[(size_t)(m0 + urow) * HH + ng * 16 + uq * 4 + q] = hvv;
            }
            unsigned long long pk = (unsigned long long)hv[0]
                                  | ((unsigned long long)hv[1] << 16)
                                  | ((unsigned long long)hv[2] << 32)
                                  | ((unsigned long long)hv[3] << 48);
            asm volatile("global_store_dwordx2 %0, %1, off sc0 sc1" :: "v"(sb), "v"(pk) : "memory");
            if (s + 1 < SS && tid < 32)
                clsS[cur ^ 1][tid] = x[(size_t)(m0 + tid) * SS + s + 1];
        }

        // ---- one-hop barrier: drain h-stores, atomic arrival, poll counter ----
        if (s < SS - 1) {
            asm volatile("s_waitcnt vmcnt(0)" ::: "memory");   // h-store drained at L3
            __syncthreads();
            if (tid == 0) {
                int one = 1;
                asm volatile("global_atomic_add %0, %1, off"
                             :: "v"(ctrAddr), "v"(one) : "memory");
            }
            PRLOAD(pr, clsS[cur ^ 1]);     // next step's proj gather, rides the poll
            const int tv = (s + 1) << 6;   // 64 WGs per mg-group
            int got;
            do {   // lane-uniform single-line poll
                asm volatile("global_load_dword %0, %1, off sc0 sc1\n\t"
                             "s_waitcnt vmcnt(0)"
                             : "=v"(got) : "v"(ctrAddr) : "memory");
            } while (got < tv);
        }
    }
}

// ---------------- final projection + log_softmax ----------------
__global__ void k_final(const float* __restrict__ hf32, const float* __restrict__ Wph,
                        const float* __restrict__ bp, float* __restrict__ out) {
    __shared__ float red[128];
    int b = blockIdx.x, c = threadIdx.x;
    const float* hr = hf32 + (size_t)b * HH;
    float acc = bp[c];
    for (int k = 0; k < HH; k++) acc += hr[k] * Wph[(size_t)k * NCC + c];
    red[c] = acc;
    __syncthreads();
    for (int st = 64; st > 0; st >>= 1) {
        if (c < st) red[c] = fmaxf(red[c], red[c + st]);
        __syncthreads();
    }
    float m = red[0];
    __syncthreads();
    red[c] = __expf(acc - m);
    __syncthreads();
    for (int st = 64; st > 0; st >>= 1) {
        if (c < st) red[c] += red[c + st];
        __syncthreads();
    }
    out[(size_t)b * NCC + c] = acc - m - __logf(red[0]);
}

extern "C" void kernel_launch(void* const* d_in, const int* in_sizes, int n_in,
                              void* d_out, int out_size, void* d_ws, size_t ws_size,
                              hipStream_t stream) {
    const int*   x   = (const int*)  d_in[0];
    const float* emb = (const float*)d_in[1];
    const float* Wfx = (const float*)d_in[2];
    const float* Wfh = (const float*)d_in[3];
    const float* bf_ = (const float*)d_in[4];
    const float* Wix = (const float*)d_in[5];
    const float* Wih = (const float*)d_in[6];
    const float* bi_ = (const float*)d_in[7];
    const float* Wgx = (const float*)d_in[8];
    const float* Wgh = (const float*)d_in[9];
    const float* bg_ = (const float*)d_in[10];
    const float* Wox = (const float*)d_in[11];
    const float* Woh = (const float*)d_in[12];
    const float* bo_ = (const float*)d_in[13];
    const float* Wph = (const float*)d_in[14];
    const float* bp_ = (const float*)d_in[15];
    float* out = (float*)d_out;

    char* ws = (char*)d_ws;
    unsigned short* WhT   = (unsigned short*)(ws);              // 8 MB
    float*          proj  = (float*)(ws + 8388608);             // 2.02 MB -> ends 10502144
    int*            flags = (int*)(ws + 10502656);              // 64 KB (16384 ints)
    unsigned short* hb0   = (unsigned short*)(ws + 10568192);   // 256 KB
    unsigned short* hb1   = (unsigned short*)(ws + 10830336);   // 256 KB
    float*          hf32  = (float*)(ws + 11092480);            // 512 KB -> ends ~11.6 MB

    k_pre<<<dim3(6672), dim3(256), 0, stream>>>(hb0, flags, Wfh, Wih, Wgh, Woh, WhT,
                                                emb, Wfx, Wix, Wgx, Wox,
                                                bf_, bi_, bg_, bo_, proj);
    k_scan<<<dim3(NWG), dim3(128), 0, stream>>>(x, proj, WhT, hb0, hb1, hf32, flags);
    k_final<<<dim3(128), dim3(128), 0, stream>>>(hf32, Wph, bp_, out);
}